// Round 2
// baseline (379.834 us; speedup 1.0000x reference)
//
#include <hip/hip_runtime.h>
#include <stdint.h>

// Problem constants (from reference setup_inputs)
#define NB 32
#define NN 6000
#define NM 128
#define NL 81
#define NT (NB * NN)                 // 192000 (b,n) pairs
// randint spans/multipliers: span = count*10 - 1; mult = (2^16 % span)^2 % span
#define SPAN_P 1279u
#define MULT_P 882u
#define SPAN_N 3839u
#define MULT_N 1588u
#define K_POS 128u
#define K_NEG 384u

// Output geometry: deltas [B,N,81,4] floats ++ labels [B,N,81] floats
#define DELTA_FLOATS ((size_t)NT * NL * 4)        // 62,208,000
#define LABEL_FLOATS ((size_t)NT * NL)            // 15,552,000
#define DELTA_VEC4 (DELTA_FLOATS / 4)             // 15,552,000 float4s
#define LABEL_VEC4 (LABEL_FLOATS / 4)             //  3,888,000 float4s
#define TOTAL_VEC4 (DELTA_VEC4 + LABEL_VEC4)      // 19,440,000 float4s = 311 MB

// ---------------- Threefry-2x32 (JAX key schedule, 20 rounds) ----------------
__host__ __device__ __forceinline__ uint32_t rotl32(uint32_t v, uint32_t r) {
  return (v << r) | (v >> (32u - r));
}

__host__ __device__ inline void threefry2x32(uint32_t k0, uint32_t k1,
                                             uint32_t x0, uint32_t x1,
                                             uint32_t& o0, uint32_t& o1) {
  uint32_t kb = k0 ^ k1 ^ 0x1BD11BDAu;
#define TF_ROUND(r) { x0 += x1; x1 = rotl32(x1, r); x1 ^= x0; }
  x0 += k0; x1 += k1;
  TF_ROUND(13u) TF_ROUND(15u) TF_ROUND(26u) TF_ROUND(6u)
  x0 += k1; x1 += kb + 1u;
  TF_ROUND(17u) TF_ROUND(29u) TF_ROUND(16u) TF_ROUND(24u)
  x0 += kb; x1 += k0 + 2u;
  TF_ROUND(13u) TF_ROUND(15u) TF_ROUND(26u) TF_ROUND(6u)
  x0 += k0; x1 += k1 + 3u;
  TF_ROUND(17u) TF_ROUND(29u) TF_ROUND(16u) TF_ROUND(24u)
  x0 += k1; x1 += kb + 4u;
  TF_ROUND(13u) TF_ROUND(15u) TF_ROUND(26u) TF_ROUND(6u)
  x0 += kb; x1 += k0 + 5u;
#undef TF_ROUND
  o0 = x0; o1 = x1;
}

// ---------------- Kernel A: IoU max/argmax + masks + PRNG scores ----------------
// iou = inter / (bbox_area + 0 - inter)   [gt_area==0 bug kept, fp32 exact order]
// pos: merged>0.5; neg: 0.1<merged<0.5. Scores use partitionable-threefry
// semantics: bits(key,t) = o0^o1 of tf(key,(0,t)); randint combine per jax.
// Also initializes the per-row decision array dlab[t] = -1 (no selection).
__global__ __launch_bounds__(256) void iou_mask_score(
    const float* __restrict__ roi, const float* __restrict__ gt,
    uint16_t* __restrict__ scp, uint16_t* __restrict__ scn,
    uint8_t* __restrict__ midx, int* __restrict__ dlab,
    uint32_t k1p0, uint32_t k1p1, uint32_t k2p0, uint32_t k2p1,
    uint32_t k1n0, uint32_t k1n1, uint32_t k2n0, uint32_t k2n1)
{
#pragma clang fp contract(off)
  __shared__ float4 g[NM];
  int b = blockIdx.y;
  if (threadIdx.x < NM)
    g[threadIdx.x] = reinterpret_cast<const float4*>(gt)[b * NM + threadIdx.x];
  __syncthreads();
  int n = blockIdx.x * 256 + threadIdx.x;
  if (n >= NN) return;
  size_t t = (size_t)b * NN + n;
  float4 r = reinterpret_cast<const float4*>(roi)[t];
  float by1 = r.x, bx1 = r.y, by2 = r.z, bx2 = r.w;   // (y1,x1,y2,x2)
  float area = (by2 - by1) * (bx2 - bx1);
  float best = -INFINITY; int bi = 0;
  for (int j = 0; j < NM; ++j) {
    float4 q = g[j];                                   // (gy1,gx1,gy2,gx2)
    float xt = fmaxf(bx1, q.y), yt = fmaxf(by1, q.x);
    float xb = fminf(bx2, q.w), yb = fminf(by2, q.z);
    float inter = fmaxf(xb - xt, 0.0f) * fmaxf(yb - yt, 0.0f);
    float uni = area - inter;          // bbox_area + gt_area(=0) - inter
    float iou = inter / uni;
    if (iou > best) { best = iou; bi = j; }   // strict > == first argmax (np/jnp)
  }
  bool pos = best > 0.5f;
  bool neg = (best < 0.5f) && (best > 0.1f);
  uint16_t sp = 0, sn = 0;
  uint32_t a0, a1;
  if (pos) {
    uint32_t h, l;
    threefry2x32(k1p0, k1p1, 0u, (uint32_t)t, a0, a1); h = a0 ^ a1;
    threefry2x32(k2p0, k2p1, 0u, (uint32_t)t, a0, a1); l = a0 ^ a1;
    sp = (uint16_t)(1u + ((h % SPAN_P) * MULT_P + (l % SPAN_P)) % SPAN_P);
  }
  if (neg) {
    uint32_t h, l;
    threefry2x32(k1n0, k1n1, 0u, (uint32_t)t, a0, a1); h = a0 ^ a1;
    threefry2x32(k2n0, k2n1, 0u, (uint32_t)t, a0, a1); l = a0 ^ a1;
    sn = (uint16_t)(1u + ((h % SPAN_N) * MULT_N + (l % SPAN_N)) % SPAN_N);
  }
  scp[t] = sp; scn[t] = sn; midx[t] = (uint8_t)bi;
  dlab[t] = -1;
}

// ---------------- Kernel C': per-row stable top-K selection -> compact marks ----------------
// Stable descending argsort over int scores == keep all score>T plus the first
// (K - count(>T)) index-ordered entries with score==T (T = K-th largest score).
// T via LDS histogram + suffix scan; ties via index-ordered chunked prefix scan.
// Instead of scattering into the 311MB output (which would have to be ordered
// after a full zero-fill), writes a compact decision per row:
//   dlab[t] = label slot (0..80) or stays -1;  ddelta[t] = delta float4 (zero for neg).
__global__ __launch_bounds__(256) void select_mark(
    const uint16_t* __restrict__ scp, const uint16_t* __restrict__ scn,
    const uint8_t* __restrict__ midx,
    const float* __restrict__ roi, const float* __restrict__ gt,
    const int* __restrict__ glab,
    int* __restrict__ dlab, float4* __restrict__ ddelta)
{
#pragma clang fp contract(off)
  __shared__ uint32_t hist[3840];
  __shared__ uint32_t csum[256];
  __shared__ uint32_t cpref[256];
  __shared__ int shT;
  __shared__ uint32_t shRem;
  int tid = threadIdx.x;
  int b = blockIdx.x & 31;
  int type = blockIdx.x >> 5;           // 0 = pos, 1 = neg
  const uint16_t* sc = (type ? scn : scp) + (size_t)b * NN;
  const int S = type ? 3840 : 1280;     // bins (scores are 1..S-1)
  const uint32_t K = type ? K_NEG : K_POS;

  for (int s = tid; s < S; s += 256) hist[s] = 0u;
  if (tid == 0) { shT = 0; shRem = 0u; }
  __syncthreads();
  for (int n = tid; n < NN; n += 256) {
    uint32_t s = sc[n];
    if (s) atomicAdd(&hist[s], 1u);
  }
  __syncthreads();
  // suffix scan over bins to find threshold T and rem = K - count(score > T)
  const int cb = S >> 8;                // 5 (pos) or 15 (neg) bins per thread
  int lo = tid * cb, hi = lo + cb;
  uint32_t ms = 0;
  for (int s = lo; s < hi; ++s) ms += hist[s];
  csum[tid] = ms;
  __syncthreads();
  if (tid == 0) {
    uint32_t run = 0;
    for (int c = 255; c >= 0; --c) { cpref[c] = run; run += csum[c]; }
  }
  __syncthreads();
  {
    uint32_t cum = cpref[tid];          // count of scores strictly above this chunk
    for (int s = hi - 1; s >= lo; --s) {
      uint32_t h = hist[s];
      if (h != 0u && cum < K && cum + h >= K) { shT = s; shRem = K - cum; }
      cum += h;
    }
  }
  __syncthreads();
  const int T = shT;                     // 0 => fewer than K masked: keep all
  const uint32_t rem = shRem;
  // index-ordered rank among score==T entries (contiguous 24-wide chunks)
  const int CH = 24;                     // 256*24 >= 6000
  int n0 = tid * CH, n1 = n0 + CH; if (n1 > NN) n1 = NN;
  uint32_t ec = 0;
  if (T > 0) { for (int n = n0; n < n1; ++n) if (sc[n] == (uint16_t)T) ++ec; }
  csum[tid] = ec;
  __syncthreads();
  if (tid == 0) { uint32_t run = 0; for (int c = 0; c < 256; ++c) { cpref[c] = run; run += csum[c]; } }
  __syncthreads();
  uint32_t tr = cpref[tid];
  for (int n = n0; n < n1; ++n) {
    uint32_t s = sc[n];
    if (!s) continue;
    bool keep;
    if ((int)s > T) keep = true;
    else if ((int)s == T) { keep = (tr < rem); ++tr; }
    else keep = false;
    if (!keep) continue;
    size_t t = (size_t)b * NN + n;
    if (type) {
      // negative: exp_lab = 0 -> one_hot slot 0 = 1; deltas row all zero
      dlab[t] = 0;
      ddelta[t] = make_float4(0.0f, 0.0f, 0.0f, 0.0f);
    } else {
      int mi = midx[t];
      int lab = glab[b * NM + mi];
      float4 r = reinterpret_cast<const float4*>(roi)[t];
      float4 q = reinterpret_cast<const float4*>(gt)[(size_t)b * NM + mi];
      float by1 = r.x, bx1 = r.y, by2 = r.z, bx2 = r.w;
      float gy1 = q.x, gx1 = q.y, gy2 = q.z, gx2 = q.w;
      float bw = bx2 - bx1, bh = by2 - by1;
      float bcx = bx1 + 0.5f * bw, bcy = by1 + 0.5f * bh;
      float gw = gx2 - gx1, gh = gy2 - gy1;
      float gcx = gx1 + 0.5f * gw, gcy = gy1 + 0.5f * gh;
      if (bw == 0.0f) bw = 1e-3f;
      if (bh == 0.0f) bh = 1e-3f;
      float dx = (gw == 0.0f) ? 0.0f : (gcx - bcx) / bw;
      float dy = (gh == 0.0f) ? 0.0f : (gcy - bcy) / bh;
      // use precise log (libm) to stay within ulps of np.log
      float dw = (gw == 0.0f) ? 0.0f : logf(gw / bw);
      float dh = (gh == 0.0f) ? 0.0f : logf(gh / bh);
      dlab[t] = lab;
      ddelta[t] = make_float4(dy, dx, dh, dw);   // stack([dy,dx,dh,dw])
    }
  }
}

// ---------------- Kernel F: single value-correct streaming write of the output ----------------
// Flat float4 grid-stride over the whole 311MB output. Each element derives its
// (row t, slot s) and emits zero / ddelta[t] / one-hot 1.0 from dlab[t].
// dlab is 768KB (L1/L2-resident broadcast loads); pure streaming stores.
__global__ __launch_bounds__(256) void write_out(
    const int* __restrict__ dlab, const float4* __restrict__ ddelta,
    float4* __restrict__ out4)
{
  const float4 z = make_float4(0.0f, 0.0f, 0.0f, 0.0f);
  uint32_t gsz = gridDim.x * 256u;
  for (uint32_t i = blockIdx.x * 256u + threadIdx.x; i < (uint32_t)TOTAL_VEC4; i += gsz) {
    float4 v = z;
    if (i < (uint32_t)DELTA_VEC4) {
      // deltas region: one float4 per (t, slot)
      uint32_t t = i / (uint32_t)NL;           // const-div -> mul_hi
      uint32_t s = i - t * (uint32_t)NL;       // 0..80
      int L = dlab[t];
      if ((int)s == L) v = ddelta[t];
    } else {
      // labels region: 4 floats per float4; rows are 81 floats (may straddle)
      uint32_t f = (i - (uint32_t)DELTA_VEC4) * 4u;   // float offset in label region
      uint32_t t = f / (uint32_t)NL;
      uint32_t s = f - t * (uint32_t)NL;
      if (s <= (uint32_t)(NL - 4)) {           // all 4 elems in row t
        int L = dlab[t];
        v.x = ((int)s     == L) ? 1.0f : 0.0f;
        v.y = ((int)s + 1 == L) ? 1.0f : 0.0f;
        v.z = ((int)s + 2 == L) ? 1.0f : 0.0f;
        v.w = ((int)s + 3 == L) ? 1.0f : 0.0f;
      } else {                                  // straddles row boundary
        float vv[4];
#pragma unroll
        for (int j = 0; j < 4; ++j) {
          uint32_t fj = f + (uint32_t)j;
          uint32_t tj = fj / (uint32_t)NL;
          uint32_t sj = fj - tj * (uint32_t)NL;
          vv[j] = ((int)sj == dlab[tj]) ? 1.0f : 0.0f;
        }
        v.x = vv[0]; v.y = vv[1]; v.z = vv[2]; v.w = vv[3];
      }
    }
    out4[i] = v;
  }
}

extern "C" void kernel_launch(void* const* d_in, const int* in_sizes, int n_in,
                              void* d_out, int out_size, void* d_ws, size_t ws_size,
                              hipStream_t stream) {
  (void)in_sizes; (void)n_in; (void)ws_size; (void)out_size;
  const float* roi = (const float*)d_in[0];   // fp32 [32,6000,4]
  const float* gt  = (const float*)d_in[1];   // fp32 [32,128,4]
  const int* glab  = (const int*)d_in[2];     // int32 [32,128]
  float* out = (float*)d_out;                 // fp32: deltas [B,N,81,4] ++ labels [B,N,81]

  // workspace layout (16B-aligned first): ddelta, dlab, scp, scn, midx  (~4.8 MB)
  float4* ddelta = (float4*)d_ws;
  int* dlab = (int*)(ddelta + NT);
  uint16_t* scp = (uint16_t*)(dlab + NT);
  uint16_t* scn = scp + NT;
  uint8_t*  midx = (uint8_t*)(scn + NT);

  // Host-side JAX key derivation (threefry_partitionable=True semantics):
  // key(42) = (0,42); foldlike split -> keys[i] = tf(key,(0,i)); randint splits again.
  uint32_t kp0, kp1, kn0, kn1;
  threefry2x32(0u, 42u, 0u, 0u, kp0, kp1);   // kp (positive sampling key)
  threefry2x32(0u, 42u, 0u, 1u, kn0, kn1);   // kn (negative sampling key)
  uint32_t k1p0, k1p1, k2p0, k2p1, k1n0, k1n1, k2n0, k2n1;
  threefry2x32(kp0, kp1, 0u, 0u, k1p0, k1p1);  // higher-bits key (pos)
  threefry2x32(kp0, kp1, 0u, 1u, k2p0, k2p1);  // lower-bits key (pos)
  threefry2x32(kn0, kn1, 0u, 0u, k1n0, k1n1);  // higher-bits key (neg)
  threefry2x32(kn0, kn1, 0u, 1u, k2n0, k2n1);  // lower-bits key (neg)

  dim3 gridA(24, 32);   // ceil(6000/256) x B
  iou_mask_score<<<gridA, 256, 0, stream>>>(roi, gt, scp, scn, midx, dlab,
      k1p0, k1p1, k2p0, k2p1, k1n0, k1n1, k2n0, k2n1);
  select_mark<<<64, 256, 0, stream>>>(scp, scn, midx, roi, gt, glab, dlab, ddelta);
  write_out<<<2048, 256, 0, stream>>>(dlab, ddelta, (float4*)out);
}

// Round 3
// 365.484 us; speedup vs baseline: 1.0393x; 1.0393x over previous
//
#include <hip/hip_runtime.h>
#include <stdint.h>

// Problem constants (from reference setup_inputs)
#define NB 32
#define NN 6000
#define NM 128
#define NL 81
#define NT (NB * NN)                 // 192000 (b,n) pairs
// randint spans/multipliers: span = count*10 - 1; mult = (2^16 % span)^2 % span
#define SPAN_P 1279u
#define MULT_P 882u
#define SPAN_N 3839u
#define MULT_N 1588u
#define K_POS 128u
#define K_NEG 384u

// Total output floats: deltas [B,N,81,4] ++ labels [B,N,81] = NT*NL*5
#define OUT_FLOATS ((size_t)NT * NL * 5)          // 77,760,000
#define OUT_VEC4 (OUT_FLOATS / 4)                 // 19,440,000 float4s (311 MB)

typedef float f32x4 __attribute__((ext_vector_type(4)));

// ---------------- Threefry-2x32 (JAX key schedule, 20 rounds) ----------------
__host__ __device__ __forceinline__ uint32_t rotl32(uint32_t v, uint32_t r) {
  return (v << r) | (v >> (32u - r));
}

__host__ __device__ inline void threefry2x32(uint32_t k0, uint32_t k1,
                                             uint32_t x0, uint32_t x1,
                                             uint32_t& o0, uint32_t& o1) {
  uint32_t kb = k0 ^ k1 ^ 0x1BD11BDAu;
#define TF_ROUND(r) { x0 += x1; x1 = rotl32(x1, r); x1 ^= x0; }
  x0 += k0; x1 += k1;
  TF_ROUND(13u) TF_ROUND(15u) TF_ROUND(26u) TF_ROUND(6u)
  x0 += k1; x1 += kb + 1u;
  TF_ROUND(17u) TF_ROUND(29u) TF_ROUND(16u) TF_ROUND(24u)
  x0 += kb; x1 += k0 + 2u;
  TF_ROUND(13u) TF_ROUND(15u) TF_ROUND(26u) TF_ROUND(6u)
  x0 += k0; x1 += k1 + 3u;
  TF_ROUND(17u) TF_ROUND(29u) TF_ROUND(16u) TF_ROUND(24u)
  x0 += k1; x1 += kb + 4u;
  TF_ROUND(13u) TF_ROUND(15u) TF_ROUND(26u) TF_ROUND(6u)
  x0 += kb; x1 += k0 + 5u;
#undef TF_ROUND
  o0 = x0; o1 = x1;
}

// ---------------- Kernel A: fused zero-fill + IoU max/argmax + PRNG scores ----------------
// Phase 0: grid-stride NON-TEMPORAL float4 zero of the full 311MB output.
//          nt stores bypass L2 (zeros have no reuse; avoids evicting 32MB of
//          L2 for nothing). Stores are issued before the IoU loop so the
//          store drain overlaps the VALU-bound IoU scan; no barrier between.
// Phase 1: iou = inter / (bbox_area + 0 - inter)  [gt_area==0 bug kept, fp32
//          exact order]; pos: merged>0.5; neg: 0.1<merged<0.5. Scores use
//          partitionable-threefry semantics exactly as jax.random.randint.
__global__ __launch_bounds__(256) void iou_mask_score(
    const float* __restrict__ roi, const float* __restrict__ gt,
    uint16_t* __restrict__ scp, uint16_t* __restrict__ scn,
    uint8_t* __restrict__ midx, float* __restrict__ out,
    uint32_t k1p0, uint32_t k1p1, uint32_t k2p0, uint32_t k2p1,
    uint32_t k1n0, uint32_t k1n1, uint32_t k2n0, uint32_t k2n1)
{
#pragma clang fp contract(off)
  __shared__ float4 g[NM];
  int b = blockIdx.y;
  if (threadIdx.x < NM)
    g[threadIdx.x] = reinterpret_cast<const float4*>(gt)[b * NM + threadIdx.x];
  __syncthreads();

  // ---- Phase 0: zero-fill the output (all threads; nt = bypass L2) ----
  {
    f32x4* o4 = reinterpret_cast<f32x4*>(out);
    const f32x4 z = {0.0f, 0.0f, 0.0f, 0.0f};
    uint32_t gthreads = gridDim.x * gridDim.y * 256u;                // 196,608
    uint32_t i0 = (blockIdx.y * gridDim.x + blockIdx.x) * 256u + threadIdx.x;
    for (uint32_t i = i0; i < (uint32_t)OUT_VEC4; i += gthreads)
      __builtin_nontemporal_store(z, &o4[i]);
  }

  // ---- Phase 1: IoU + masks + scores (stores above drain concurrently) ----
  int n = blockIdx.x * 256 + threadIdx.x;
  if (n >= NN) return;
  size_t t = (size_t)b * NN + n;
  float4 r = reinterpret_cast<const float4*>(roi)[t];
  float by1 = r.x, bx1 = r.y, by2 = r.z, bx2 = r.w;   // (y1,x1,y2,x2)
  float area = (by2 - by1) * (bx2 - bx1);
  float best = -INFINITY; int bi = 0;
  for (int j = 0; j < NM; ++j) {
    float4 q = g[j];                                   // (gy1,gx1,gy2,gx2)
    float xt = fmaxf(bx1, q.y), yt = fmaxf(by1, q.x);
    float xb = fminf(bx2, q.w), yb = fminf(by2, q.z);
    float inter = fmaxf(xb - xt, 0.0f) * fmaxf(yb - yt, 0.0f);
    float uni = area - inter;          // bbox_area + gt_area(=0) - inter
    float iou = inter / uni;
    if (iou > best) { best = iou; bi = j; }   // strict > == first argmax (np/jnp)
  }
  bool pos = best > 0.5f;
  bool neg = (best < 0.5f) && (best > 0.1f);
  uint16_t sp = 0, sn = 0;
  uint32_t a0, a1;
  if (pos) {
    uint32_t h, l;
    threefry2x32(k1p0, k1p1, 0u, (uint32_t)t, a0, a1); h = a0 ^ a1;
    threefry2x32(k2p0, k2p1, 0u, (uint32_t)t, a0, a1); l = a0 ^ a1;
    sp = (uint16_t)(1u + ((h % SPAN_P) * MULT_P + (l % SPAN_P)) % SPAN_P);
  }
  if (neg) {
    uint32_t h, l;
    threefry2x32(k1n0, k1n1, 0u, (uint32_t)t, a0, a1); h = a0 ^ a1;
    threefry2x32(k2n0, k2n1, 0u, (uint32_t)t, a0, a1); l = a0 ^ a1;
    sn = (uint16_t)(1u + ((h % SPAN_N) * MULT_N + (l % SPAN_N)) % SPAN_N);
  }
  scp[t] = sp; scn[t] = sn; midx[t] = (uint8_t)bi;
}

// ---------------- Kernel C: per-row stable top-K selection + sparse scatter ----------------
// Stable descending argsort over int scores == keep all score>T plus the first
// (K - count(>T)) index-ordered entries with score==T (T = K-th largest score).
// T via LDS histogram + suffix scan; ties via index-ordered chunked prefix scan.
// Scatters directly into the zeroed output (stream-ordered after kernel A):
// ~16K sparse writes total, negligible traffic.
__global__ __launch_bounds__(256) void select_write(
    const uint16_t* __restrict__ scp, const uint16_t* __restrict__ scn,
    const uint8_t* __restrict__ midx,
    const float* __restrict__ roi, const float* __restrict__ gt,
    const int* __restrict__ glab,
    float* __restrict__ out)
{
#pragma clang fp contract(off)
  __shared__ uint32_t hist[3840];
  __shared__ uint32_t csum[256];
  __shared__ uint32_t cpref[256];
  __shared__ int shT;
  __shared__ uint32_t shRem;
  int tid = threadIdx.x;
  int b = blockIdx.x & 31;
  int type = blockIdx.x >> 5;           // 0 = pos, 1 = neg
  const uint16_t* sc = (type ? scn : scp) + (size_t)b * NN;
  const int S = type ? 3840 : 1280;     // bins (scores are 1..S-1)
  const uint32_t K = type ? K_NEG : K_POS;

  for (int s = tid; s < S; s += 256) hist[s] = 0u;
  if (tid == 0) { shT = 0; shRem = 0u; }
  __syncthreads();
  for (int n = tid; n < NN; n += 256) {
    uint32_t s = sc[n];
    if (s) atomicAdd(&hist[s], 1u);
  }
  __syncthreads();
  // suffix scan over bins to find threshold T and rem = K - count(score > T)
  const int cb = S >> 8;                // 5 (pos) or 15 (neg) bins per thread
  int lo = tid * cb, hi = lo + cb;
  uint32_t ms = 0;
  for (int s = lo; s < hi; ++s) ms += hist[s];
  csum[tid] = ms;
  __syncthreads();
  if (tid == 0) {
    uint32_t run = 0;
    for (int c = 255; c >= 0; --c) { cpref[c] = run; run += csum[c]; }
  }
  __syncthreads();
  {
    uint32_t cum = cpref[tid];          // count of scores strictly above this chunk
    for (int s = hi - 1; s >= lo; --s) {
      uint32_t h = hist[s];
      if (h != 0u && cum < K && cum + h >= K) { shT = s; shRem = K - cum; }
      cum += h;
    }
  }
  __syncthreads();
  const int T = shT;                     // 0 => fewer than K masked: keep all
  const uint32_t rem = shRem;
  // index-ordered rank among score==T entries (contiguous 24-wide chunks)
  const int CH = 24;                     // 256*24 >= 6000
  int n0 = tid * CH, n1 = n0 + CH; if (n1 > NN) n1 = NN;
  uint32_t ec = 0;
  if (T > 0) { for (int n = n0; n < n1; ++n) if (sc[n] == (uint16_t)T) ++ec; }
  csum[tid] = ec;
  __syncthreads();
  if (tid == 0) { uint32_t run = 0; for (int c = 0; c < 256; ++c) { cpref[c] = run; run += csum[c]; } }
  __syncthreads();
  uint32_t tr = cpref[tid];
  const size_t labBase = (size_t)NT * NL * 4;   // floats in deltas region
  for (int n = n0; n < n1; ++n) {
    uint32_t s = sc[n];
    if (!s) continue;
    bool keep;
    if ((int)s > T) keep = true;
    else if ((int)s == T) { keep = (tr < rem); ++tr; }
    else keep = false;
    if (!keep) continue;
    size_t t = (size_t)b * NN + n;
    if (type) {
      // negative: exp_lab = 0 -> one_hot slot 0 = 1; deltas row all zero
      out[labBase + t * (size_t)NL] = 1.0f;
    } else {
      int mi = midx[t];
      int lab = glab[b * NM + mi];
      float4 r = reinterpret_cast<const float4*>(roi)[t];
      float4 q = reinterpret_cast<const float4*>(gt)[(size_t)b * NM + mi];
      float by1 = r.x, bx1 = r.y, by2 = r.z, bx2 = r.w;
      float gy1 = q.x, gx1 = q.y, gy2 = q.z, gx2 = q.w;
      float bw = bx2 - bx1, bh = by2 - by1;
      float bcx = bx1 + 0.5f * bw, bcy = by1 + 0.5f * bh;
      float gw = gx2 - gx1, gh = gy2 - gy1;
      float gcx = gx1 + 0.5f * gw, gcy = gy1 + 0.5f * gh;
      if (bw == 0.0f) bw = 1e-3f;
      if (bh == 0.0f) bh = 1e-3f;
      float dx = (gw == 0.0f) ? 0.0f : (gcx - bcx) / bw;
      float dy = (gh == 0.0f) ? 0.0f : (gcy - bcy) / bh;
      // precise log (libm) to stay within ulps of np.log
      float dw = (gw == 0.0f) ? 0.0f : logf(gw / bw);
      float dh = (gh == 0.0f) ? 0.0f : logf(gh / bh);
      float4 d; d.x = dy; d.y = dx; d.z = dh; d.w = dw;   // stack([dy,dx,dh,dw])
      reinterpret_cast<float4*>(out)[t * (size_t)NL + lab] = d;
      out[labBase + t * (size_t)NL + lab] = 1.0f;
    }
  }
}

extern "C" void kernel_launch(void* const* d_in, const int* in_sizes, int n_in,
                              void* d_out, int out_size, void* d_ws, size_t ws_size,
                              hipStream_t stream) {
  (void)in_sizes; (void)n_in; (void)ws_size; (void)out_size;
  const float* roi = (const float*)d_in[0];   // fp32 [32,6000,4]
  const float* gt  = (const float*)d_in[1];   // fp32 [32,128,4]
  const int* glab  = (const int*)d_in[2];     // int32 [32,128]
  float* out = (float*)d_out;                 // fp32: deltas [B,N,81,4] ++ labels [B,N,81]

  // workspace: pos scores (u16), neg scores (u16), argmax idx (u8) -> 960 KB
  uint16_t* scp = (uint16_t*)d_ws;
  uint16_t* scn = scp + NT;
  uint8_t*  midx = (uint8_t*)(scn + NT);

  // Host-side JAX key derivation (threefry_partitionable=True semantics):
  // key(42) = (0,42); foldlike split -> keys[i] = tf(key,(0,i)); randint splits again.
  uint32_t kp0, kp1, kn0, kn1;
  threefry2x32(0u, 42u, 0u, 0u, kp0, kp1);   // kp (positive sampling key)
  threefry2x32(0u, 42u, 0u, 1u, kn0, kn1);   // kn (negative sampling key)
  uint32_t k1p0, k1p1, k2p0, k2p1, k1n0, k1n1, k2n0, k2n1;
  threefry2x32(kp0, kp1, 0u, 0u, k1p0, k1p1);  // higher-bits key (pos)
  threefry2x32(kp0, kp1, 0u, 1u, k2p0, k2p1);  // lower-bits key (pos)
  threefry2x32(kn0, kn1, 0u, 0u, k1n0, k1n1);  // higher-bits key (neg)
  threefry2x32(kn0, kn1, 0u, 1u, k2n0, k2n1);  // lower-bits key (neg)

  // Zero-fill fused into kernel A (nt float4 stores, 311 MB at streaming rate,
  // overlapped with the IoU scan). Sparse scatter afterwards in select_write.
  dim3 gridA(24, 32);   // ceil(6000/256) x B
  iou_mask_score<<<gridA, 256, 0, stream>>>(roi, gt, scp, scn, midx, out,
      k1p0, k1p1, k2p0, k2p1, k1n0, k1n1, k2n0, k2n1);
  select_write<<<64, 256, 0, stream>>>(scp, scn, midx, roi, gt, glab, out);
}